// Round 5
// baseline (551.889 us; speedup 1.0000x reference)
//
#include <hip/hip_runtime.h>
#include <hip/hip_bf16.h>

// Problem constants
#define Bsz 65536
#define Sdim 256
#define Aag 8
#define Kk 10
#define ADdim 128

// Per-k slab: [key-net 43008B][agents-net 43008B][action-net 59392B] = 145408 B
// R8 layout: weights are read DIRECTLY from global (L2-resident, 1.45MB total) — no LDS,
// no barriers. Chunk-major storage: W1/W2 elem off = (j*64 + n)*8, W3 = (j*16 + r)*8,
// where n = g-permuted row, j = 16B k-chunk. A wave's 64 lanes then read 4 contiguous
// 256B runs per load instruction (q-groups 1KB apart) — coalesced for L2 service.
// XOR bank-swizzle removed (it was an LDS artifact).
#define SLAB_K_ELEMS 72704
#define NET_ELEMS 21504   // elems per 43008-byte net

typedef float f32x4 __attribute__((ext_vector_type(4)));
typedef __bf16 bf16x8 __attribute__((ext_vector_type(8)));

#define MFMA(a, b, cacc) __builtin_amdgcn_mfma_f32_16x16x32_bf16((a), (b), (cacc), 0, 0, 0)

// R5: native cast — gfx950 lowers fptrunc f32->bf16 to v_cvt_pk_bf16_f32 (HW RNE).
__device__ __forceinline__ __bf16 f2bf(float f) {
    return (__bf16)f;
}

__device__ __forceinline__ unsigned int pack_bf2(float a, float b) {
    union { unsigned short s[2]; unsigned int u; } cv;
    union { unsigned short s; __bf16 b; } x;
    x.b = f2bf(a); cv.s[0] = x.s;
    x.b = f2bf(b); cv.s[1] = x.s;
    return cv.u;
}

__device__ __forceinline__ bf16x8 cvt8(float4 lo, float4 hi) {
    bf16x8 v;
    v[0] = f2bf(lo.x); v[1] = f2bf(lo.y); v[2] = f2bf(lo.z); v[3] = f2bf(lo.w);
    v[4] = f2bf(hi.x); v[5] = f2bf(hi.y); v[6] = f2bf(hi.z); v[7] = f2bf(hi.w);
    return v;
}

// Hidden-neuron permutation: C-layout position n = mt*16 + q*4 + i holds original neuron g(n).
// g(n) = (mt>>1)*32 + q*8 + (mt&1)*4 + i  ->  lane q's regs (mt=2kb+jh, i) are exactly
// B-frag element j=4*jh+i for k = kb*32 + q*8 + j (original order).
__device__ __forceinline__ int gperm(int n) {
    return ((n >> 5) << 5) + (((n >> 2) & 3) << 3) + (((n >> 4) & 1) << 2) + (n & 3);
}

// ---------------- prep: fp32 weights -> row-permuted, chunk-major bf16 slabs ----------------
__global__ void prep_weights(const float* __restrict__ kW1, const float* __restrict__ aW1,
                             const float* __restrict__ cW1, const float* __restrict__ kW2,
                             const float* __restrict__ aW2, const float* __restrict__ cW2,
                             const float* __restrict__ kW3, const float* __restrict__ aW3,
                             const float* __restrict__ cW3, __bf16* __restrict__ out) {
    int gid = blockIdx.x * 256 + threadIdx.x;  // one thread per 16B chunk
    if (gid >= 90880) return;
    int k = gid / 9088;
    int r = gid - k * 9088;
    int t, cn;
    if (r < 2688)      { t = 0; cn = r; }
    else if (r < 5376) { t = 1; cn = r - 2688; }
    else               { t = 2; cn = r - 5376; }
    const int KN = (t == 2) ? 384 : 256;
    const int CPR = KN / 8;
    const float* W1 = (t == 0) ? kW1 : (t == 1) ? aW1 : cW1;
    const float* W2 = (t == 0) ? kW2 : (t == 1) ? aW2 : cW2;
    const float* W3 = (t == 0) ? kW3 : (t == 1) ? aW3 : cW3;
    const int rows3 = (t == 0) ? 1 : 8;
    int dstchunk;
    const float* src = nullptr;
    if (cn < 64 * CPR) {
        int n = cn / CPR, k8 = cn - n * CPR;              // n = permuted-space row, k8 = chunk
        src = W1 + ((size_t)(k * 64 + gperm(n))) * KN + k8 * 8;
        dstchunk = k8 * 64 + n;                           // chunk-major
    } else if (cn < 64 * CPR + 512) {
        int c2 = cn - 64 * CPR;
        int n = c2 >> 3, k8 = c2 & 7;
        src = W2 + ((size_t)(k * 64 + gperm(n))) * 64 + k8 * 8;   // rows permuted
        dstchunk = 64 * CPR + k8 * 64 + n;                // chunk-major
    } else {
        int c3 = cn - 64 * CPR - 512;
        int n = c3 >> 3, k8 = c3 & 7;                     // n = padded row 0..15
        if (n < rows3) src = W3 + ((size_t)(k * rows3 + n)) * 64 + k8 * 8;  // unpermuted
        dstchunk = 64 * CPR + 512 + k8 * 16 + n;          // chunk-major
    }
    bf16x8 v;
#pragma unroll
    for (int e = 0; e < 8; ++e) v[e] = src ? f2bf(src[e]) : (__bf16)0.0f;
    *(bf16x8*)(out + (size_t)k * SLAB_K_ELEMS + t * NET_ELEMS + dstchunk * 8) = v;
}

// Build next layer's B-fragment (k-block kb) from this lane's own packed h words.
__device__ __forceinline__ bf16x8 frag_from_hp(const unsigned int (&hp)[4][2], int kb) {
    int4 u = {(int)hp[kb * 2][0], (int)hp[kb * 2][1], (int)hp[kb * 2 + 1][0], (int)hp[kb * 2 + 1][1]};
    return __builtin_bit_cast(bf16x8, u);
}

// ---------------- one net (3-layer MLP), role-swapped: D = W . x^T, weights from GLOBAL ----
// MODE 0: key (abs+broadcast), 1: agents (sigmoid), 2: action (sigmoid+combine, KB=12)
// 16 batch rows per wave (s-dim removed vs R2) -> half the acc/xf pressure, fits 128 VGPRs
// at 4 waves/SIMD.
template <int KB, int MODE>
__device__ __forceinline__ void compute_net(
    const __bf16* __restrict__ W, const bf16x8 (&xf)[8], const bf16x8 (&xa)[4],
    int q, int c, int k,
    const float* __restrict__ b1p, const float* __restrict__ b2p, const float* __restrict__ b3p,
    float& keyv, float (&ag)[4], float (&outacc)[4]) {
    constexpr int CPR = KB * 4;          // W1 chunks per row
    constexpr int W2O = 64 * CPR * 8;    // elem offset of W2
    constexpr int W3O = W2O + 4096;      // elem offset of W3

    // ---- layer 1: A = W1 (global, chunk-major, row-permuted), B = x (registers) ----
    f32x4 acc[4];
#pragma unroll
    for (int mt = 0; mt < 4; ++mt) {
        int base = ((mt >> 1) << 5) + (q << 3) + ((mt & 1) << 2);  // g-permuted bias index
        float4 bv = *(const float4*)(b1p + k * 64 + base);
        acc[mt] = {bv.x, bv.y, bv.z, bv.w};
    }
#pragma unroll
    for (int kb = 0; kb < KB; ++kb) {
        bf16x8 b = (kb < 8) ? xf[kb] : xa[kb - 8];
#pragma unroll
        for (int mt = 0; mt < 4; ++mt) {
            // elem off = ((kb*4+q)*64 + mt*16 + c) * 8
            bf16x8 a = *(const bf16x8*)(W + ((kb * 256 + q * 64 + mt * 16 + c) << 3));
            acc[mt] = MFMA(a, b, acc[mt]);
        }
    }
    // relu -> packed bf16 pairs; position (q,mt,i) holds h1[kb*32+q*8+j] by construction
    unsigned int hp[4][2];
#pragma unroll
    for (int mt = 0; mt < 4; ++mt) {
        hp[mt][0] = pack_bf2(fmaxf(acc[mt][0], 0.f), fmaxf(acc[mt][1], 0.f));
        hp[mt][1] = pack_bf2(fmaxf(acc[mt][2], 0.f), fmaxf(acc[mt][3], 0.f));
    }

    // ---- layer 2: A = W2 (global, row-permuted), B = h1 (own registers!) ----
    f32x4 acc2[4];
#pragma unroll
    for (int mt = 0; mt < 4; ++mt) {
        int base = ((mt >> 1) << 5) + (q << 3) + ((mt & 1) << 2);
        float4 bv = *(const float4*)(b2p + k * 64 + base);
        acc2[mt] = {bv.x, bv.y, bv.z, bv.w};
    }
#pragma unroll
    for (int kb = 0; kb < 2; ++kb) {
        bf16x8 bh = frag_from_hp(hp, kb);
#pragma unroll
        for (int mt = 0; mt < 4; ++mt) {
            bf16x8 a2 = *(const bf16x8*)(W + W2O + ((kb * 256 + q * 64 + mt * 16 + c) << 3));
            acc2[mt] = MFMA(a2, bh, acc2[mt]);
        }
    }
#pragma unroll
    for (int mt = 0; mt < 4; ++mt) {
        hp[mt][0] = pack_bf2(fmaxf(acc2[mt][0], 0.f), fmaxf(acc2[mt][1], 0.f));
        hp[mt][1] = pack_bf2(fmaxf(acc2[mt][2], 0.f), fmaxf(acc2[mt][3], 0.f));
    }

    // ---- layer 3: A = W3 padded to 16 rows (global, unpermuted), B = h2 ----
    f32x4 acc3;
    if (MODE == 0) {
        float b3 = b3p[k];
        f32x4 z = {0.f, 0.f, 0.f, 0.f};
        if (q == 0) z[0] = b3;
        acc3 = z;
    } else {
        f32x4 z = {0.f, 0.f, 0.f, 0.f};
        if (q < 2) {
            float4 bv = *(const float4*)(b3p + k * 8 + q * 4);
            z = {bv.x, bv.y, bv.z, bv.w};
        }
        acc3 = z;
    }
#pragma unroll
    for (int kb = 0; kb < 2; ++kb) {
        // elem off = ((kb*4+q)*16 + c) * 8 — wave reads one contiguous 1KB run
        bf16x8 a3 = *(const bf16x8*)(W + W3O + ((kb * 64 + q * 16 + c) << 3));
        acc3 = MFMA(a3, frag_from_hp(hp, kb), acc3);
    }
    // ---- epilogue (C-layout: out-row = q*4+i, batch col = c) ----
    if (MODE == 0) {
        float v = __shfl(acc3[0], c, 64);  // row 0 lives in lanes 0..15 reg 0
        keyv = fabsf(v) + 1e-10f;
    } else if (MODE == 1) {
#pragma unroll
        for (int i = 0; i < 4; ++i) ag[i] = 1.f / (1.f + __expf(-acc3[i]));
    } else {
#pragma unroll
        for (int i = 0; i < 4; ++i)
            outacc[i] += keyv * ag[i] * (1.f / (1.f + __expf(-acc3[i])));
    }
}

// ---------------- main kernel: 256 thr (4 waves), grid 1024, ZERO LDS, zero barriers --------
// R8: weights (1.45MB) are L2-resident — LDS staging was caching data the cache hierarchy
// already serves (guide common-mistake #7). Dropping it removes 30 barriers + staging drains
// and lifts the LDS occupancy cap: 16 rows/wave at <=128 VGPRs -> 4 waves/SIMD (2x R2's TLP).
// Total weight traffic 4096 waves x 145KB ~= 0.6GB ~= 17us of L2 BW.
__global__ __launch_bounds__(256, 4) void qplex_main(
    const float* __restrict__ states, const float* __restrict__ actions,
    const __bf16* __restrict__ wbf,
    const float* __restrict__ b1k, const float* __restrict__ b2k, const float* __restrict__ b3k,
    const float* __restrict__ b1a, const float* __restrict__ b2a, const float* __restrict__ b3a,
    const float* __restrict__ b1c, const float* __restrict__ b2c, const float* __restrict__ b3c,
    float* __restrict__ out) {
    const int tid = threadIdx.x;
    const int lane = tid & 63;
    const int wave = tid >> 6;
    const int q = lane >> 4;
    const int c = lane & 15;
    const int row = blockIdx.x * 64 + wave * 16 + c;   // this lane's batch row

    // ---- states as B-fragments: lane (q,c) holds k = kb*32 + q*8 + j of row `row` ----
    bf16x8 xf[8];
    {
        const float* srow = states + (size_t)row * Sdim + q * 8;
#pragma unroll
        for (int kb = 0; kb < 8; ++kb)
            xf[kb] = cvt8(*(const float4*)(srow + kb * 32), *(const float4*)(srow + kb * 32 + 4));
    }
    // ---- actions converted ONCE (16 VGPRs) — was re-read fp32 from L3 every k (335MB) ----
    bf16x8 xa[4];
    {
        const float* arow = actions + (size_t)row * ADdim + q * 8;
#pragma unroll
        for (int kb = 0; kb < 4; ++kb)
            xa[kb] = cvt8(*(const float4*)(arow + kb * 32), *(const float4*)(arow + kb * 32 + 4));
    }

    float keyv = 0.f;
    float ag[4] = {0.f, 0.f, 0.f, 0.f};
    float outacc[4] = {0.f, 0.f, 0.f, 0.f};

#pragma unroll 1
    for (int k = 0; k < Kk; ++k) {
        const __bf16* kslab = wbf + (size_t)k * SLAB_K_ELEMS;
        compute_net<8, 0>(kslab, xf, xa, q, c, k, b1k, b2k, b3k, keyv, ag, outacc);
        compute_net<8, 1>(kslab + NET_ELEMS, xf, xa, q, c, k, b1a, b2a, b3a, keyv, ag, outacc);
        compute_net<12, 2>(kslab + 2 * NET_ELEMS, xf, xa, q, c, k, b1c, b2c, b3c, keyv, ag, outacc);
    }

    // ---- store: rows q*4+i are agents (q<2), batch row = row ----
    if (q < 2) {
        float4 v = {outacc[0], outacc[1], outacc[2], outacc[3]};
        *(float4*)(out + (size_t)row * Aag + q * 4) = v;
    }
}

extern "C" void kernel_launch(void* const* d_in, const int* in_sizes, int n_in,
                              void* d_out, int out_size, void* d_ws, size_t ws_size,
                              hipStream_t stream) {
    const float* states = (const float*)d_in[0];
    const float* actions = (const float*)d_in[1];
    const float* kW1 = (const float*)d_in[2];
    const float* kb1 = (const float*)d_in[3];
    const float* kW2 = (const float*)d_in[4];
    const float* kb2 = (const float*)d_in[5];
    const float* kW3 = (const float*)d_in[6];
    const float* kb3 = (const float*)d_in[7];
    const float* aW1 = (const float*)d_in[8];
    const float* ab1 = (const float*)d_in[9];
    const float* aW2 = (const float*)d_in[10];
    const float* ab2 = (const float*)d_in[11];
    const float* aW3 = (const float*)d_in[12];
    const float* ab3 = (const float*)d_in[13];
    const float* cW1 = (const float*)d_in[14];
    const float* cb1 = (const float*)d_in[15];
    const float* cW2 = (const float*)d_in[16];
    const float* cb2 = (const float*)d_in[17];
    const float* cW3 = (const float*)d_in[18];
    const float* cb3 = (const float*)d_in[19];
    float* out = (float*)d_out;
    __bf16* wbf = (__bf16*)d_ws;  // 1,454,080 bytes of scratch

    prep_weights<<<355, 256, 0, stream>>>(kW1, aW1, cW1, kW2, aW2, cW2, kW3, aW3, cW3, wbf);
    qplex_main<<<1024, 256, 0, stream>>>(states, actions, wbf, kb1, kb2, kb3,
                                         ab1, ab2, ab3, cb1, cb2, cb3, out);
}

// Round 6
// 279.751 us; speedup vs baseline: 1.9728x; 1.9728x over previous
//
#include <hip/hip_runtime.h>
#include <hip/hip_bf16.h>

// Problem constants
#define Bsz 65536
#define Sdim 256
#define Aag 8
#define Kk 10
#define ADdim 128

// Per-k slab: [key-net 43008B][agents-net 43008B][action-net 59392B] = 145408 B
// Net layout (16B chunks, XOR-swizzled): W1 64 x CPR chunks, W2 64x8, W3 16x8 (zero-padded rows)
// W1/W2 ROWS are stored in g-permuted order so MFMA C-layout == next layer's B-fragment layout.
// R9: back to the R2 swizzled-LDS layout (R8's L2-direct chunk-major failed on load latency:
// MfmaUtil 9%, every MFMA behind a ~200cyc L2 load).
#define SLAB_K_ELEMS 72704
#define NET_ELEMS 21504   // elems per 43008-byte net

typedef float f32x4 __attribute__((ext_vector_type(4)));
typedef __bf16 bf16x8 __attribute__((ext_vector_type(8)));

#define MFMA(a, b, cacc) __builtin_amdgcn_mfma_f32_16x16x32_bf16((a), (b), (cacc), 0, 0, 0)

// R5: native cast — gfx950 lowers fptrunc f32->bf16 to v_cvt_pk_bf16_f32 (HW RNE).
__device__ __forceinline__ __bf16 f2bf(float f) {
    return (__bf16)f;
}

__device__ __forceinline__ unsigned int pack_bf2(float a, float b) {
    union { unsigned short s[2]; unsigned int u; } cv;
    union { unsigned short s; __bf16 b; } x;
    x.b = f2bf(a); cv.s[0] = x.s;
    x.b = f2bf(b); cv.s[1] = x.s;
    return cv.u;
}

__device__ __forceinline__ bf16x8 cvt8(float4 lo, float4 hi) {
    bf16x8 v;
    v[0] = f2bf(lo.x); v[1] = f2bf(lo.y); v[2] = f2bf(lo.z); v[3] = f2bf(lo.w);
    v[4] = f2bf(hi.x); v[5] = f2bf(hi.y); v[6] = f2bf(hi.z); v[7] = f2bf(hi.w);
    return v;
}

// Hidden-neuron permutation: C-layout position n = mt*16 + q*4 + i holds original neuron g(n).
__device__ __forceinline__ int gperm(int n) {
    return ((n >> 5) << 5) + (((n >> 2) & 3) << 3) + (((n >> 4) & 1) << 2) + (n & 3);
}

// ---------------- prep: fp32 weights -> XOR-swizzled, row-permuted bf16 slabs (R2 layout) ----
__global__ void prep_weights(const float* __restrict__ kW1, const float* __restrict__ aW1,
                             const float* __restrict__ cW1, const float* __restrict__ kW2,
                             const float* __restrict__ aW2, const float* __restrict__ cW2,
                             const float* __restrict__ kW3, const float* __restrict__ aW3,
                             const float* __restrict__ cW3, __bf16* __restrict__ out) {
    int gid = blockIdx.x * 256 + threadIdx.x;  // one thread per 16B chunk
    if (gid >= 90880) return;
    int k = gid / 9088;
    int r = gid - k * 9088;
    int t, cn;
    if (r < 2688)      { t = 0; cn = r; }
    else if (r < 5376) { t = 1; cn = r - 2688; }
    else               { t = 2; cn = r - 5376; }
    const int KN = (t == 2) ? 384 : 256;
    const int CPR = KN / 8;
    const float* W1 = (t == 0) ? kW1 : (t == 1) ? aW1 : cW1;
    const float* W2 = (t == 0) ? kW2 : (t == 1) ? aW2 : cW2;
    const float* W3 = (t == 0) ? kW3 : (t == 1) ? aW3 : cW3;
    const int rows3 = (t == 0) ? 1 : 8;
    int dstchunk;
    const float* src = nullptr;
    if (cn < 64 * CPR) {
        int n = cn / CPR, k8 = cn - n * CPR;              // n = permuted-space row
        src = W1 + ((size_t)(k * 64 + gperm(n))) * KN + k8 * 8;
        dstchunk = n * CPR + (k8 ^ (n & 7));
    } else if (cn < 64 * CPR + 512) {
        int c2 = cn - 64 * CPR;
        int n = c2 >> 3, k8 = c2 & 7;
        src = W2 + ((size_t)(k * 64 + gperm(n))) * 64 + k8 * 8;   // rows permuted, k-cols original
        dstchunk = 64 * CPR + n * 8 + (k8 ^ (n & 7));
    } else {
        int c3 = cn - 64 * CPR - 512;
        int n = c3 >> 3, k8 = c3 & 7;
        if (n < rows3) src = W3 + ((size_t)(k * rows3 + n)) * 64 + k8 * 8;  // unpermuted
        dstchunk = 64 * CPR + 512 + n * 8 + (k8 ^ (n & 7));
    }
    bf16x8 v;
#pragma unroll
    for (int e = 0; e < 8; ++e) v[e] = src ? f2bf(src[e]) : (__bf16)0.0f;
    *(bf16x8*)(out + (size_t)k * SLAB_K_ELEMS + t * NET_ELEMS + dstchunk * 8) = v;
}

// ---------------- async staging: slab -> LDS, 1KB per wave-instruction ----------------
__device__ __forceinline__ void stage(const __bf16* __restrict__ src, __bf16* dst,
                                      int nchunks, int wave, int lane) {
    const char* g = (const char*)src + lane * 16;
    for (int ci = wave; ci < nchunks; ci += 8) {
        __builtin_amdgcn_global_load_lds(
            (const __attribute__((address_space(1))) void*)(g + ci * 1024),
            (__attribute__((address_space(3))) void*)((char*)dst + ci * 1024), 16, 0, 0);
    }
}

// Build next layer's B-fragment (k-block kb) from this lane's own packed h words.
__device__ __forceinline__ bf16x8 frag_from_hp(const unsigned int (&hp)[4][2], int kb) {
    int4 u = {(int)hp[kb * 2][0], (int)hp[kb * 2][1], (int)hp[kb * 2 + 1][0], (int)hp[kb * 2 + 1][1]};
    return __builtin_bit_cast(bf16x8, u);
}

// ---------------- one net (3-layer MLP), role-swapped: D = W . x^T (R2 verbatim) ----------
// MODE 0: key (abs+broadcast), 1: agents (sigmoid), 2: action (sigmoid+combine)
// MODE 2 re-reads its extra 128 x-columns (actions) from global fp32 each call so the
// fragments are TRANSIENT (die after layer 1) instead of 32 permanently-live VGPRs.
template <int KB, int MODE>
__device__ __forceinline__ void compute_net(
    const __bf16* __restrict__ W, const bf16x8 (&xf)[2][8],
    const float* __restrict__ actions, int rowbase,
    int q, int c, int k,
    const float* __restrict__ b1p, const float* __restrict__ b2p, const float* __restrict__ b3p,
    float (&keyv)[2], float (&ag)[2][4], float (&outacc)[2][4]) {
    constexpr int CPR = KB * 4;          // W1 chunks per row
    constexpr int W2O = 64 * CPR * 8;    // elem offset of W2
    constexpr int W3O = W2O + 4096;      // elem offset of W3

    // transient action-x fragments (MODE 2 only); loads issue ~32 MFMAs before first use
    bf16x8 xa[2][4];
    if (MODE == 2) {
#pragma unroll
        for (int s = 0; s < 2; ++s) {
            const float* ap = actions + (size_t)(rowbase + s * 16 + c) * ADdim + q * 8;
#pragma unroll
            for (int kb = 0; kb < 4; ++kb)
                xa[s][kb] = cvt8(*(const float4*)(ap + kb * 32), *(const float4*)(ap + kb * 32 + 4));
        }
    }

    // ---- layer 1: A = W1' (LDS, swizzled, row-permuted), B = x (registers) ----
    f32x4 acc[4][2];
#pragma unroll
    for (int mt = 0; mt < 4; ++mt) {
        int base = ((mt >> 1) << 5) + (q << 3) + ((mt & 1) << 2);  // g-permuted bias index
        float4 bv = *(const float4*)(b1p + k * 64 + base);
        f32x4 b = {bv.x, bv.y, bv.z, bv.w};
        acc[mt][0] = b; acc[mt][1] = b;
    }
#pragma unroll
    for (int kb = 0; kb < KB; ++kb) {
        bf16x8 b0 = (kb < 8) ? xf[0][kb] : xa[0][kb - 8];
        bf16x8 b1 = (kb < 8) ? xf[1][kb] : xa[1][kb - 8];
#pragma unroll
        for (int mt = 0; mt < 4; ++mt) {
            int n = mt * 16 + c;
            bf16x8 a = *(const bf16x8*)(W + ((n * CPR + ((kb * 4 + q) ^ (n & 7))) << 3));
            acc[mt][0] = MFMA(a, b0, acc[mt][0]);
            acc[mt][1] = MFMA(a, b1, acc[mt][1]);
        }
    }
    // relu -> packed bf16 pairs; position (q,mt,i) holds h1[kb*32+q*8+j] by construction
    unsigned int hp[2][4][2];
#pragma unroll
    for (int s = 0; s < 2; ++s)
#pragma unroll
        for (int mt = 0; mt < 4; ++mt) {
            hp[s][mt][0] = pack_bf2(fmaxf(acc[mt][s][0], 0.f), fmaxf(acc[mt][s][1], 0.f));
            hp[s][mt][1] = pack_bf2(fmaxf(acc[mt][s][2], 0.f), fmaxf(acc[mt][s][3], 0.f));
        }

    // ---- layer 2: A = W2' (LDS, row-permuted), B = h1 (own registers!) ----
    f32x4 acc2[4][2];
#pragma unroll
    for (int mt = 0; mt < 4; ++mt) {
        int base = ((mt >> 1) << 5) + (q << 3) + ((mt & 1) << 2);
        float4 bv = *(const float4*)(b2p + k * 64 + base);
        f32x4 b = {bv.x, bv.y, bv.z, bv.w};
        acc2[mt][0] = b; acc2[mt][1] = b;
    }
#pragma unroll
    for (int kb = 0; kb < 2; ++kb) {
        bf16x8 bh0 = frag_from_hp(hp[0], kb);
        bf16x8 bh1 = frag_from_hp(hp[1], kb);
#pragma unroll
        for (int mt = 0; mt < 4; ++mt) {
            int n = mt * 16 + c;
            bf16x8 a2 = *(const bf16x8*)(W + W2O + ((n * 8 + ((kb * 4 + q) ^ (n & 7))) << 3));
            acc2[mt][0] = MFMA(a2, bh0, acc2[mt][0]);
            acc2[mt][1] = MFMA(a2, bh1, acc2[mt][1]);
        }
    }
    // relu -> packed h2 (same permuted property)
#pragma unroll
    for (int s = 0; s < 2; ++s)
#pragma unroll
        for (int mt = 0; mt < 4; ++mt) {
            hp[s][mt][0] = pack_bf2(fmaxf(acc2[mt][s][0], 0.f), fmaxf(acc2[mt][s][1], 0.f));
            hp[s][mt][1] = pack_bf2(fmaxf(acc2[mt][s][2], 0.f), fmaxf(acc2[mt][s][3], 0.f));
        }

    // ---- layer 3: A = W3 padded to 16 rows (LDS, unpermuted), B = h2 (own registers) ----
    f32x4 acc3[2];
    if (MODE == 0) {
        float b3 = b3p[k];
        f32x4 z = {0.f, 0.f, 0.f, 0.f};
        if (q == 0) z[0] = b3;
        acc3[0] = z; acc3[1] = z;
    } else {
        f32x4 z = {0.f, 0.f, 0.f, 0.f};
        if (q < 2) {
            float4 bv = *(const float4*)(b3p + k * 8 + q * 4);
            z = {bv.x, bv.y, bv.z, bv.w};
        }
        acc3[0] = z; acc3[1] = z;
    }
#pragma unroll
    for (int kb = 0; kb < 2; ++kb) {
        bf16x8 a3 = *(const bf16x8*)(W + W3O + ((c * 8 + ((kb * 4 + q) ^ (c & 7))) << 3));
#pragma unroll
        for (int s = 0; s < 2; ++s) acc3[s] = MFMA(a3, frag_from_hp(hp[s], kb), acc3[s]);
    }
    // ---- epilogue (C-layout: out-row = q*4+i, batch col = c) ----
#pragma unroll
    for (int s = 0; s < 2; ++s) {
        if (MODE == 0) {
            float v = __shfl(acc3[s][0], c, 64);  // row 0 lives in lanes 0..15 reg 0
            keyv[s] = fabsf(v) + 1e-10f;
        } else if (MODE == 1) {
#pragma unroll
            for (int i = 0; i < 4; ++i) ag[s][i] = 1.f / (1.f + __expf(-acc3[s][i]));
        } else {
#pragma unroll
            for (int i = 0; i < 4; ++i)
                outacc[s][i] += keyv[s] * ag[s][i] * (1.f / (1.f + __expf(-acc3[s][i])));
        }
    }
}

// ---------------- main kernel: 512 thr, grid 256 (1 block/CU), 2-phase LDS schedule --------
// R9: R2's proven per-net compute (fits 128 VGPRs, no spill) + R6's 2-phase barrier schedule:
// region A = key+agents (86016 B), region B = action (59392 B). Barriers 3/k -> 2/k, and the
// key-net tail (pack/shfl/sigmoid VALU) can overlap the agents-net head (MFMA) since no
// barrier separates the two sequential compute_net calls. R3/R4 lesson: do NOT fuse the
// net loop bodies — 2x live acc/hp exceeds the 128-reg allocation and spills (~200B/thread).
__global__ __launch_bounds__(512, 1) void qplex_main(
    const float* __restrict__ states, const float* __restrict__ actions,
    const __bf16* __restrict__ wbf,
    const float* __restrict__ b1k, const float* __restrict__ b2k, const float* __restrict__ b3k,
    const float* __restrict__ b1a, const float* __restrict__ b2a, const float* __restrict__ b3a,
    const float* __restrict__ b1c, const float* __restrict__ b2c, const float* __restrict__ b3c,
    float* __restrict__ out) {
    __shared__ __bf16 WB[SLAB_K_ELEMS];  // 145408 B: [A: key||agents 43008 elems][B: action]
    __bf16* RA = WB;
    __bf16* RB = WB + 2 * NET_ELEMS;

    const int tid = threadIdx.x;
    const int lane = tid & 63;
    const int wave = tid >> 6;
    const int q = lane >> 4;
    const int c = lane & 15;
    const int rowbase = blockIdx.x * 256 + wave * 32;

    // kick off staging of slab-0 key+agents before anything else
    stage(wbf, RA, 84, wave, lane);

    // ---- load this wave's 32 rows of states as B-fragments (lane c: row rowbase+s*16+c) ----
    bf16x8 xf[2][8];
#pragma unroll
    for (int s = 0; s < 2; ++s) {
        const float* srow = states + (size_t)(rowbase + s * 16 + c) * Sdim + q * 8;
#pragma unroll
        for (int kb = 0; kb < 8; ++kb)
            xf[s][kb] = cvt8(*(const float4*)(srow + kb * 32), *(const float4*)(srow + kb * 32 + 4));
    }

    float keyv[2];
    float ag[2][4];
    float outacc[2][4];
#pragma unroll
    for (int s = 0; s < 2; ++s) {
        keyv[s] = 0.f;
#pragma unroll
        for (int i = 0; i < 4; ++i) { ag[s][i] = 0.f; outacc[s][i] = 0.f; }
    }

    __syncthreads();  // drains slab-0 key+agents staging (vmcnt0 before barrier)

    for (int k = 0; k < Kk; ++k) {
        const __bf16* kslab = wbf + (size_t)k * SLAB_K_ELEMS;
        // --- phase A: key then agents (region A, sequential — no barrier between);
        //     prefetch action net -> region B ---
        stage(kslab + 2 * NET_ELEMS, RB, 58, wave, lane);
        compute_net<8, 0>(RA, xf, actions, rowbase, q, c, k,
                          b1k, b2k, b3k, keyv, ag, outacc);
        compute_net<8, 1>(RA + NET_ELEMS, xf, actions, rowbase, q, c, k,
                          b1a, b2a, b3a, keyv, ag, outacc);
        __syncthreads();
        // --- phase B: action net (region B); prefetch next slab's key+agents -> region A ---
        if (k < Kk - 1) stage(kslab + SLAB_K_ELEMS, RA, 84, wave, lane);
        compute_net<12, 2>(RB, xf, actions, rowbase, q, c, k,
                           b1c, b2c, b3c, keyv, ag, outacc);
        __syncthreads();
    }

    // ---- store: rows q*4+i are agents a (q<2), col c is batch ----
    if (q < 2) {
#pragma unroll
        for (int s = 0; s < 2; ++s) {
            int r = rowbase + s * 16 + c;
            float4 v = {outacc[s][0], outacc[s][1], outacc[s][2], outacc[s][3]};
            *(float4*)(out + (size_t)r * Aag + q * 4) = v;
        }
    }
}

extern "C" void kernel_launch(void* const* d_in, const int* in_sizes, int n_in,
                              void* d_out, int out_size, void* d_ws, size_t ws_size,
                              hipStream_t stream) {
    const float* states = (const float*)d_in[0];
    const float* actions = (const float*)d_in[1];
    const float* kW1 = (const float*)d_in[2];
    const float* kb1 = (const float*)d_in[3];
    const float* kW2 = (const float*)d_in[4];
    const float* kb2 = (const float*)d_in[5];
    const float* kW3 = (const float*)d_in[6];
    const float* kb3 = (const float*)d_in[7];
    const float* aW1 = (const float*)d_in[8];
    const float* ab1 = (const float*)d_in[9];
    const float* aW2 = (const float*)d_in[10];
    const float* ab2 = (const float*)d_in[11];
    const float* aW3 = (const float*)d_in[12];
    const float* ab3 = (const float*)d_in[13];
    const float* cW1 = (const float*)d_in[14];
    const float* cb1 = (const float*)d_in[15];
    const float* cW2 = (const float*)d_in[16];
    const float* cb2 = (const float*)d_in[17];
    const float* cW3 = (const float*)d_in[18];
    const float* cb3 = (const float*)d_in[19];
    float* out = (float*)d_out;
    __bf16* wbf = (__bf16*)d_ws;  // 1,454,080 bytes of scratch

    prep_weights<<<355, 256, 0, stream>>>(kW1, aW1, cW1, kW2, aW2, cW2, kW3, aW3, cW3, wbf);
    qplex_main<<<256, 512, 0, stream>>>(states, actions, wbf, kb1, kb2, kb3,
                                        ab1, ab2, ab3, cb1, cb2, cb3, out);
}

// Round 7
// 259.201 us; speedup vs baseline: 2.1292x; 1.0793x over previous
//
#include <hip/hip_runtime.h>
#include <hip/hip_bf16.h>

// Problem constants
#define Bsz 65536
#define Sdim 256
#define Aag 8
#define Kk 10
#define ADdim 128

// Per-k slab: [key-net 43008B][agents-net 43008B][action-net 59392B] = 145408 B
// R10 layout: STREAM-ORDERED. Each wave's ds_read sequence is static, so chunks are stored
// in exact consumption order: read i, lane l at byte i*1024 + l*16 within the net.
//   W1: read i = kb*4+mt (KB*4 reads), holds source chunk (row n=mt*16+c gperm'd, k8=kb*4+q)
//   W2: read i = kb*4+mt (8 reads), base CPR*1024 bytes
//   W3: read i = kb     (2 reads), base CPR*1024+8192 bytes
// Compute reads become ds_read_b128 [one base VGPR + imm offset]: zero per-read VALU address
// math (was ~500 ops/wave/k of XOR-swizzle arithmetic) and linear lane addressing (2
// lanes/bank = conflict-free; old layout was 8-way-conflicted: 9.17M conflict cycles).
#define SLAB_K_ELEMS 72704
#define NET_ELEMS 21504   // elems per 43008-byte net

typedef float f32x4 __attribute__((ext_vector_type(4)));
typedef __bf16 bf16x8 __attribute__((ext_vector_type(8)));

#define MFMA(a, b, cacc) __builtin_amdgcn_mfma_f32_16x16x32_bf16((a), (b), (cacc), 0, 0, 0)

// R5: native cast — gfx950 lowers fptrunc f32->bf16 to v_cvt_pk_bf16_f32 (HW RNE).
__device__ __forceinline__ __bf16 f2bf(float f) {
    return (__bf16)f;
}

__device__ __forceinline__ unsigned int pack_bf2(float a, float b) {
    union { unsigned short s[2]; unsigned int u; } cv;
    union { unsigned short s; __bf16 b; } x;
    x.b = f2bf(a); cv.s[0] = x.s;
    x.b = f2bf(b); cv.s[1] = x.s;
    return cv.u;
}

__device__ __forceinline__ bf16x8 cvt8(float4 lo, float4 hi) {
    bf16x8 v;
    v[0] = f2bf(lo.x); v[1] = f2bf(lo.y); v[2] = f2bf(lo.z); v[3] = f2bf(lo.w);
    v[4] = f2bf(hi.x); v[5] = f2bf(hi.y); v[6] = f2bf(hi.z); v[7] = f2bf(hi.w);
    return v;
}

// Hidden-neuron permutation: C-layout position n = mt*16 + q*4 + i holds original neuron g(n).
__device__ __forceinline__ int gperm(int n) {
    return ((n >> 5) << 5) + (((n >> 2) & 3) << 3) + (((n >> 4) & 1) << 2) + (n & 3);
}

// ---------------- prep: fp32 weights -> row-permuted, STREAM-ORDERED bf16 slabs -------------
__global__ void prep_weights(const float* __restrict__ kW1, const float* __restrict__ aW1,
                             const float* __restrict__ cW1, const float* __restrict__ kW2,
                             const float* __restrict__ aW2, const float* __restrict__ cW2,
                             const float* __restrict__ kW3, const float* __restrict__ aW3,
                             const float* __restrict__ cW3, __bf16* __restrict__ out) {
    int gid = blockIdx.x * 256 + threadIdx.x;  // one thread per 16B chunk
    if (gid >= 90880) return;
    int k = gid / 9088;
    int r = gid - k * 9088;
    int t, cn;
    if (r < 2688)      { t = 0; cn = r; }
    else if (r < 5376) { t = 1; cn = r - 2688; }
    else               { t = 2; cn = r - 5376; }
    const int KN = (t == 2) ? 384 : 256;
    const int CPR = KN / 8;
    const float* W1 = (t == 0) ? kW1 : (t == 1) ? aW1 : cW1;
    const float* W2 = (t == 0) ? kW2 : (t == 1) ? aW2 : cW2;
    const float* W3 = (t == 0) ? kW3 : (t == 1) ? aW3 : cW3;
    const int rows3 = (t == 0) ? 1 : 8;
    int dstchunk;
    const float* src = nullptr;
    if (cn < 64 * CPR) {
        int n = cn / CPR, k8 = cn - n * CPR;              // n = consumed-space row, k8 = chunk
        src = W1 + ((size_t)(k * 64 + gperm(n))) * KN + k8 * 8;
        // consumed by lane (q=k8&3, c=n&15) at read i = (k8>>2)*4 + (n>>4)
        dstchunk = (((k8 >> 2) << 2) + (n >> 4)) * 64 + ((k8 & 3) << 4) + (n & 15);
    } else if (cn < 64 * CPR + 512) {
        int c2 = cn - 64 * CPR;
        int n = c2 >> 3, k8 = c2 & 7;
        src = W2 + ((size_t)(k * 64 + gperm(n))) * 64 + k8 * 8;   // rows permuted
        dstchunk = 64 * CPR + (((k8 >> 2) << 2) + (n >> 4)) * 64 + ((k8 & 3) << 4) + (n & 15);
    } else {
        int c3 = cn - 64 * CPR - 512;
        int n = c3 >> 3, k8 = c3 & 7;                     // n = padded row 0..15 (= lane c)
        if (n < rows3) src = W3 + ((size_t)(k * rows3 + n)) * 64 + k8 * 8;  // unpermuted
        dstchunk = 64 * CPR + 512 + ((k8 >> 2) << 6) + ((k8 & 3) << 4) + n;
    }
    bf16x8 v;
#pragma unroll
    for (int e = 0; e < 8; ++e) v[e] = src ? f2bf(src[e]) : (__bf16)0.0f;
    *(bf16x8*)(out + (size_t)k * SLAB_K_ELEMS + t * NET_ELEMS + dstchunk * 8) = v;
}

// ---------------- async staging: slab -> LDS, 1KB per wave-instruction ----------------
__device__ __forceinline__ void stage(const __bf16* __restrict__ src, __bf16* dst,
                                      int nchunks, int wave, int lane) {
    const char* g = (const char*)src + lane * 16;
    for (int ci = wave; ci < nchunks; ci += 8) {
        __builtin_amdgcn_global_load_lds(
            (const __attribute__((address_space(1))) void*)(g + ci * 1024),
            (__attribute__((address_space(3))) void*)((char*)dst + ci * 1024), 16, 0, 0);
    }
}

// Build next layer's B-fragment (k-block kb) from this lane's own packed h words.
__device__ __forceinline__ bf16x8 frag_from_hp(const unsigned int (&hp)[4][2], int kb) {
    int4 u = {(int)hp[kb * 2][0], (int)hp[kb * 2][1], (int)hp[kb * 2 + 1][0], (int)hp[kb * 2 + 1][1]};
    return __builtin_bit_cast(bf16x8, u);
}

// ---------------- one net (3-layer MLP), role-swapped: D = W . x^T ----------
// MODE 0: key (abs+broadcast), 1: agents (sigmoid), 2: action (sigmoid+combine)
// Weights arrive via stream-ordered LDS: lane's read j is at Wl + j*1024 (imm offset).
template <int KB, int MODE>
__device__ __forceinline__ void compute_net(
    const __bf16* __restrict__ W, const bf16x8 (&xf)[2][8],
    const float* __restrict__ actions, int rowbase,
    int q, int c, int lane, int k,
    const float* __restrict__ b1p, const float* __restrict__ b2p, const float* __restrict__ b3p,
    float (&keyv)[2], float (&ag)[2][4], float (&outacc)[2][4]) {
    constexpr int W2OB = KB * 4 * 1024;      // byte offset of W2 stream
    constexpr int W3OB = W2OB + 8192;        // byte offset of W3 stream
    const char* Wl = (const char*)W + lane * 16;

    // transient action-x fragments (MODE 2 only); loads issue ~32 MFMAs before first use
    bf16x8 xa[2][4];
    if (MODE == 2) {
#pragma unroll
        for (int s = 0; s < 2; ++s) {
            const float* ap = actions + (size_t)(rowbase + s * 16 + c) * ADdim + q * 8;
#pragma unroll
            for (int kb = 0; kb < 4; ++kb)
                xa[s][kb] = cvt8(*(const float4*)(ap + kb * 32), *(const float4*)(ap + kb * 32 + 4));
        }
    }

    // ---- layer 1: A = W1 (LDS stream), B = x (registers) ----
    f32x4 acc[4][2];
#pragma unroll
    for (int mt = 0; mt < 4; ++mt) {
        int base = ((mt >> 1) << 5) + (q << 3) + ((mt & 1) << 2);  // g-permuted bias index
        float4 bv = *(const float4*)(b1p + k * 64 + base);
        f32x4 b = {bv.x, bv.y, bv.z, bv.w};
        acc[mt][0] = b; acc[mt][1] = b;
    }
#pragma unroll
    for (int kb = 0; kb < KB; ++kb) {
        bf16x8 b0 = (kb < 8) ? xf[0][kb] : xa[0][kb - 8];
        bf16x8 b1 = (kb < 8) ? xf[1][kb] : xa[1][kb - 8];
#pragma unroll
        for (int mt = 0; mt < 4; ++mt) {
            bf16x8 a = *(const bf16x8*)(Wl + ((kb * 4 + mt) << 10));
            acc[mt][0] = MFMA(a, b0, acc[mt][0]);
            acc[mt][1] = MFMA(a, b1, acc[mt][1]);
        }
    }
    // relu -> packed bf16 pairs; position (q,mt,i) holds h1[kb*32+q*8+j] by construction
    unsigned int hp[2][4][2];
#pragma unroll
    for (int s = 0; s < 2; ++s)
#pragma unroll
        for (int mt = 0; mt < 4; ++mt) {
            hp[s][mt][0] = pack_bf2(fmaxf(acc[mt][s][0], 0.f), fmaxf(acc[mt][s][1], 0.f));
            hp[s][mt][1] = pack_bf2(fmaxf(acc[mt][s][2], 0.f), fmaxf(acc[mt][s][3], 0.f));
        }

    // ---- layer 2: A = W2 (LDS stream), B = h1 (own registers!) ----
    f32x4 acc2[4][2];
#pragma unroll
    for (int mt = 0; mt < 4; ++mt) {
        int base = ((mt >> 1) << 5) + (q << 3) + ((mt & 1) << 2);
        float4 bv = *(const float4*)(b2p + k * 64 + base);
        f32x4 b = {bv.x, bv.y, bv.z, bv.w};
        acc2[mt][0] = b; acc2[mt][1] = b;
    }
#pragma unroll
    for (int kb = 0; kb < 2; ++kb) {
        bf16x8 bh0 = frag_from_hp(hp[0], kb);
        bf16x8 bh1 = frag_from_hp(hp[1], kb);
#pragma unroll
        for (int mt = 0; mt < 4; ++mt) {
            bf16x8 a2 = *(const bf16x8*)(Wl + W2OB + ((kb * 4 + mt) << 10));
            acc2[mt][0] = MFMA(a2, bh0, acc2[mt][0]);
            acc2[mt][1] = MFMA(a2, bh1, acc2[mt][1]);
        }
    }
    // relu -> packed h2 (same permuted property)
#pragma unroll
    for (int s = 0; s < 2; ++s)
#pragma unroll
        for (int mt = 0; mt < 4; ++mt) {
            hp[s][mt][0] = pack_bf2(fmaxf(acc2[mt][s][0], 0.f), fmaxf(acc2[mt][s][1], 0.f));
            hp[s][mt][1] = pack_bf2(fmaxf(acc2[mt][s][2], 0.f), fmaxf(acc2[mt][s][3], 0.f));
        }

    // ---- layer 3: A = W3 padded to 16 rows (LDS stream), B = h2 (own registers) ----
    f32x4 acc3[2];
    if (MODE == 0) {
        float b3 = b3p[k];
        f32x4 z = {0.f, 0.f, 0.f, 0.f};
        if (q == 0) z[0] = b3;
        acc3[0] = z; acc3[1] = z;
    } else {
        f32x4 z = {0.f, 0.f, 0.f, 0.f};
        if (q < 2) {
            float4 bv = *(const float4*)(b3p + k * 8 + q * 4);
            z = {bv.x, bv.y, bv.z, bv.w};
        }
        acc3[0] = z; acc3[1] = z;
    }
#pragma unroll
    for (int kb = 0; kb < 2; ++kb) {
        bf16x8 a3 = *(const bf16x8*)(Wl + W3OB + (kb << 10));
#pragma unroll
        for (int s = 0; s < 2; ++s) acc3[s] = MFMA(a3, frag_from_hp(hp[s], kb), acc3[s]);
    }
    // ---- epilogue (C-layout: out-row = q*4+i, batch col = c) ----
#pragma unroll
    for (int s = 0; s < 2; ++s) {
        if (MODE == 0) {
            float v = __shfl(acc3[s][0], c, 64);  // row 0 lives in lanes 0..15 reg 0
            keyv[s] = fabsf(v) + 1e-10f;
        } else if (MODE == 1) {
#pragma unroll
            for (int i = 0; i < 4; ++i) ag[s][i] = 1.f / (1.f + __expf(-acc3[s][i]));
        } else {
#pragma unroll
            for (int i = 0; i < 4; ++i)
                outacc[s][i] += keyv[s] * ag[s][i] * (1.f / (1.f + __expf(-acc3[s][i])));
        }
    }
}

// ---------------- main kernel: 512 thr, grid 256 (1 block/CU), 2-phase LDS schedule --------
// R9 schedule (neutral vs R2 but fewer barriers): region A = key+agents (86016 B),
// region B = action (59392 B). R3/R4 lesson: do NOT fuse net loop bodies (reg spill).
__global__ __launch_bounds__(512, 1) void qplex_main(
    const float* __restrict__ states, const float* __restrict__ actions,
    const __bf16* __restrict__ wbf,
    const float* __restrict__ b1k, const float* __restrict__ b2k, const float* __restrict__ b3k,
    const float* __restrict__ b1a, const float* __restrict__ b2a, const float* __restrict__ b3a,
    const float* __restrict__ b1c, const float* __restrict__ b2c, const float* __restrict__ b3c,
    float* __restrict__ out) {
    __shared__ __bf16 WB[SLAB_K_ELEMS];  // 145408 B: [A: key||agents 43008 elems][B: action]
    __bf16* RA = WB;
    __bf16* RB = WB + 2 * NET_ELEMS;

    const int tid = threadIdx.x;
    const int lane = tid & 63;
    const int wave = tid >> 6;
    const int q = lane >> 4;
    const int c = lane & 15;
    const int rowbase = blockIdx.x * 256 + wave * 32;

    // kick off staging of slab-0 key+agents before anything else
    stage(wbf, RA, 84, wave, lane);

    // ---- load this wave's 32 rows of states as B-fragments (lane c: row rowbase+s*16+c) ----
    bf16x8 xf[2][8];
#pragma unroll
    for (int s = 0; s < 2; ++s) {
        const float* srow = states + (size_t)(rowbase + s * 16 + c) * Sdim + q * 8;
#pragma unroll
        for (int kb = 0; kb < 8; ++kb)
            xf[s][kb] = cvt8(*(const float4*)(srow + kb * 32), *(const float4*)(srow + kb * 32 + 4));
    }

    float keyv[2];
    float ag[2][4];
    float outacc[2][4];
#pragma unroll
    for (int s = 0; s < 2; ++s) {
        keyv[s] = 0.f;
#pragma unroll
        for (int i = 0; i < 4; ++i) { ag[s][i] = 0.f; outacc[s][i] = 0.f; }
    }

    __syncthreads();  // drains slab-0 key+agents staging (vmcnt0 before barrier)

    for (int k = 0; k < Kk; ++k) {
        const __bf16* kslab = wbf + (size_t)k * SLAB_K_ELEMS;
        // --- phase A: key then agents (region A, sequential — no barrier between);
        //     prefetch action net -> region B ---
        stage(kslab + 2 * NET_ELEMS, RB, 58, wave, lane);
        compute_net<8, 0>(RA, xf, actions, rowbase, q, c, lane, k,
                          b1k, b2k, b3k, keyv, ag, outacc);
        compute_net<8, 1>(RA + NET_ELEMS, xf, actions, rowbase, q, c, lane, k,
                          b1a, b2a, b3a, keyv, ag, outacc);
        __syncthreads();
        // --- phase B: action net (region B); prefetch next slab's key+agents -> region A ---
        if (k < Kk - 1) stage(kslab + SLAB_K_ELEMS, RA, 84, wave, lane);
        compute_net<12, 2>(RB, xf, actions, rowbase, q, c, lane, k,
                           b1c, b2c, b3c, keyv, ag, outacc);
        __syncthreads();
    }

    // ---- store: rows q*4+i are agents a (q<2), col c is batch ----
    if (q < 2) {
#pragma unroll
        for (int s = 0; s < 2; ++s) {
            int r = rowbase + s * 16 + c;
            float4 v = {outacc[s][0], outacc[s][1], outacc[s][2], outacc[s][3]};
            *(float4*)(out + (size_t)r * Aag + q * 4) = v;
        }
    }
}

extern "C" void kernel_launch(void* const* d_in, const int* in_sizes, int n_in,
                              void* d_out, int out_size, void* d_ws, size_t ws_size,
                              hipStream_t stream) {
    const float* states = (const float*)d_in[0];
    const float* actions = (const float*)d_in[1];
    const float* kW1 = (const float*)d_in[2];
    const float* kb1 = (const float*)d_in[3];
    const float* kW2 = (const float*)d_in[4];
    const float* kb2 = (const float*)d_in[5];
    const float* kW3 = (const float*)d_in[6];
    const float* kb3 = (const float*)d_in[7];
    const float* aW1 = (const float*)d_in[8];
    const float* ab1 = (const float*)d_in[9];
    const float* aW2 = (const float*)d_in[10];
    const float* ab2 = (const float*)d_in[11];
    const float* aW3 = (const float*)d_in[12];
    const float* ab3 = (const float*)d_in[13];
    const float* cW1 = (const float*)d_in[14];
    const float* cb1 = (const float*)d_in[15];
    const float* cW2 = (const float*)d_in[16];
    const float* cb2 = (const float*)d_in[17];
    const float* cW3 = (const float*)d_in[18];
    const float* cb3 = (const float*)d_in[19];
    float* out = (float*)d_out;
    __bf16* wbf = (__bf16*)d_ws;  // 1,454,080 bytes of scratch

    prep_weights<<<355, 256, 0, stream>>>(kW1, aW1, cW1, kW2, aW2, cW2, kW3, aW3, cW3, wbf);
    qplex_main<<<256, 512, 0, stream>>>(states, actions, wbf, kb1, kb2, kb3,
                                        ab1, ab2, ab3, cb1, cb2, cb3, out);
}

// Round 8
// 247.273 us; speedup vs baseline: 2.2319x; 1.0482x over previous
//
#include <hip/hip_runtime.h>
#include <hip/hip_bf16.h>

// Problem constants
#define Bsz 65536
#define Sdim 256
#define Aag 8
#define Kk 10
#define ADdim 128

// Per-k slab: [key-net 43008B][agents-net 43008B][action-net 59392B] = 145408 B
// R10 layout: STREAM-ORDERED. Each wave's ds_read sequence is static, so chunks are stored
// in exact consumption order: read i, lane l at byte i*1024 + l*16 within the net.
//   W1: read i = kb*4+mt (KB*4 reads), holds source chunk (row n=mt*16+c gperm'd, k8=kb*4+q)
//   W2: read i = kb*4+mt (8 reads), base CPR*1024 bytes
//   W3: read i = kb     (2 reads), base CPR*1024+8192 bytes
// Compute reads are ds_read_b128 [one base VGPR + imm offset]: zero per-read VALU address
// math and linear lane addressing (2 lanes/bank = conflict-free; R7 measured 0 conflicts).
#define SLAB_K_ELEMS 72704
#define NET_ELEMS 21504   // elems per 43008-byte net

typedef float f32x4 __attribute__((ext_vector_type(4)));
typedef __bf16 bf16x8 __attribute__((ext_vector_type(8)));

#define MFMA(a, b, cacc) __builtin_amdgcn_mfma_f32_16x16x32_bf16((a), (b), (cacc), 0, 0, 0)

// R5: native cast — gfx950 lowers fptrunc f32->bf16 to v_cvt_pk_bf16_f32 (HW RNE).
__device__ __forceinline__ __bf16 f2bf(float f) {
    return (__bf16)f;
}

__device__ __forceinline__ unsigned int pack_bf2(float a, float b) {
    union { unsigned short s[2]; unsigned int u; } cv;
    union { unsigned short s; __bf16 b; } x;
    x.b = f2bf(a); cv.s[0] = x.s;
    x.b = f2bf(b); cv.s[1] = x.s;
    return cv.u;
}

__device__ __forceinline__ bf16x8 cvt8(float4 lo, float4 hi) {
    bf16x8 v;
    v[0] = f2bf(lo.x); v[1] = f2bf(lo.y); v[2] = f2bf(lo.z); v[3] = f2bf(lo.w);
    v[4] = f2bf(hi.x); v[5] = f2bf(hi.y); v[6] = f2bf(hi.z); v[7] = f2bf(hi.w);
    return v;
}

// Hidden-neuron permutation: C-layout position n = mt*16 + q*4 + i holds original neuron g(n).
__device__ __forceinline__ int gperm(int n) {
    return ((n >> 5) << 5) + (((n >> 2) & 3) << 3) + (((n >> 4) & 1) << 2) + (n & 3);
}

// ---------------- prep: fp32 weights -> row-permuted, STREAM-ORDERED bf16 slabs -------------
__global__ void prep_weights(const float* __restrict__ kW1, const float* __restrict__ aW1,
                             const float* __restrict__ cW1, const float* __restrict__ kW2,
                             const float* __restrict__ aW2, const float* __restrict__ cW2,
                             const float* __restrict__ kW3, const float* __restrict__ aW3,
                             const float* __restrict__ cW3, __bf16* __restrict__ out) {
    int gid = blockIdx.x * 256 + threadIdx.x;  // one thread per 16B chunk
    if (gid >= 90880) return;
    int k = gid / 9088;
    int r = gid - k * 9088;
    int t, cn;
    if (r < 2688)      { t = 0; cn = r; }
    else if (r < 5376) { t = 1; cn = r - 2688; }
    else               { t = 2; cn = r - 5376; }
    const int KN = (t == 2) ? 384 : 256;
    const int CPR = KN / 8;
    const float* W1 = (t == 0) ? kW1 : (t == 1) ? aW1 : cW1;
    const float* W2 = (t == 0) ? kW2 : (t == 1) ? aW2 : cW2;
    const float* W3 = (t == 0) ? kW3 : (t == 1) ? aW3 : cW3;
    const int rows3 = (t == 0) ? 1 : 8;
    int dstchunk;
    const float* src = nullptr;
    if (cn < 64 * CPR) {
        int n = cn / CPR, k8 = cn - n * CPR;              // n = consumed-space row, k8 = chunk
        src = W1 + ((size_t)(k * 64 + gperm(n))) * KN + k8 * 8;
        // consumed by lane (q=k8&3, c=n&15) at read i = (k8>>2)*4 + (n>>4)
        dstchunk = (((k8 >> 2) << 2) + (n >> 4)) * 64 + ((k8 & 3) << 4) + (n & 15);
    } else if (cn < 64 * CPR + 512) {
        int c2 = cn - 64 * CPR;
        int n = c2 >> 3, k8 = c2 & 7;
        src = W2 + ((size_t)(k * 64 + gperm(n))) * 64 + k8 * 8;   // rows permuted
        dstchunk = 64 * CPR + (((k8 >> 2) << 2) + (n >> 4)) * 64 + ((k8 & 3) << 4) + (n & 15);
    } else {
        int c3 = cn - 64 * CPR - 512;
        int n = c3 >> 3, k8 = c3 & 7;                     // n = padded row 0..15 (= lane c)
        if (n < rows3) src = W3 + ((size_t)(k * rows3 + n)) * 64 + k8 * 8;  // unpermuted
        dstchunk = 64 * CPR + 512 + ((k8 >> 2) << 6) + ((k8 & 3) << 4) + n;
    }
    bf16x8 v;
#pragma unroll
    for (int e = 0; e < 8; ++e) v[e] = src ? f2bf(src[e]) : (__bf16)0.0f;
    *(bf16x8*)(out + (size_t)k * SLAB_K_ELEMS + t * NET_ELEMS + dstchunk * 8) = v;
}

// ---------------- async staging: slab -> LDS, 1KB per wave-instruction ----------------
__device__ __forceinline__ void stage(const __bf16* __restrict__ src, __bf16* dst,
                                      int nchunks, int wave, int lane) {
    const char* g = (const char*)src + lane * 16;
    for (int ci = wave; ci < nchunks; ci += 8) {
        __builtin_amdgcn_global_load_lds(
            (const __attribute__((address_space(1))) void*)(g + ci * 1024),
            (__attribute__((address_space(3))) void*)((char*)dst + ci * 1024), 16, 0, 0);
    }
}

// Build next layer's B-fragment (k-block kb) from this lane's own packed h words.
__device__ __forceinline__ bf16x8 frag_from_hp(const unsigned int (&hp)[4][2], int kb) {
    int4 u = {(int)hp[kb * 2][0], (int)hp[kb * 2][1], (int)hp[kb * 2 + 1][0], (int)hp[kb * 2 + 1][1]};
    return __builtin_bit_cast(bf16x8, u);
}

// ---------------- one net (3-layer MLP), role-swapped: D = W . x^T ----------
// MODE 0: key (abs+broadcast), 1: agents (sigmoid), 2: action (sigmoid+combine)
// Weights arrive via stream-ordered LDS: lane's read j is at Wl + j*1024 (imm offset).
// R11: layer-1 loop software-pipelined 1 kb-group deep (prefetch kb+1's 4 A-frags during
// kb's 8 MFMAs) — covers part of the ~120cyc ds_read latency that 2 waves/SIMD can't hide.
template <int KB, int MODE>
__device__ __forceinline__ void compute_net(
    const __bf16* __restrict__ W, const bf16x8 (&xf)[2][8],
    const float* __restrict__ actions, int rowbase,
    int q, int c, int lane, int k,
    const float* __restrict__ b1p, const float* __restrict__ b2p, const float* __restrict__ b3p,
    float (&keyv)[2], float (&ag)[2][4], float (&outacc)[2][4]) {
    constexpr int W2OB = KB * 4 * 1024;      // byte offset of W2 stream
    constexpr int W3OB = W2OB + 8192;        // byte offset of W3 stream
    const char* Wl = (const char*)W + lane * 16;

    // transient action-x fragments (MODE 2 only); loads issue ~32 MFMAs before first use
    bf16x8 xa[2][4];
    if (MODE == 2) {
#pragma unroll
        for (int s = 0; s < 2; ++s) {
            const float* ap = actions + (size_t)(rowbase + s * 16 + c) * ADdim + q * 8;
#pragma unroll
            for (int kb = 0; kb < 4; ++kb)
                xa[s][kb] = cvt8(*(const float4*)(ap + kb * 32), *(const float4*)(ap + kb * 32 + 4));
        }
    }

    // ---- layer 1: A = W1 (LDS stream), B = x (registers), 1-deep A-frag rotation ----
    f32x4 acc[4][2];
#pragma unroll
    for (int mt = 0; mt < 4; ++mt) {
        int base = ((mt >> 1) << 5) + (q << 3) + ((mt & 1) << 2);  // g-permuted bias index
        float4 bv = *(const float4*)(b1p + k * 64 + base);
        f32x4 b = {bv.x, bv.y, bv.z, bv.w};
        acc[mt][0] = b; acc[mt][1] = b;
    }
    {
        bf16x8 aw[4];
#pragma unroll
        for (int mt = 0; mt < 4; ++mt) aw[mt] = *(const bf16x8*)(Wl + (mt << 10));
#pragma unroll
        for (int kb = 0; kb < KB; ++kb) {
            bf16x8 awn[4];
            if (kb < KB - 1) {
#pragma unroll
                for (int mt = 0; mt < 4; ++mt)
                    awn[mt] = *(const bf16x8*)(Wl + (((kb + 1) * 4 + mt) << 10));
            }
            bf16x8 b0 = (kb < 8) ? xf[0][kb] : xa[0][kb - 8];
            bf16x8 b1 = (kb < 8) ? xf[1][kb] : xa[1][kb - 8];
#pragma unroll
            for (int mt = 0; mt < 4; ++mt) {
                acc[mt][0] = MFMA(aw[mt], b0, acc[mt][0]);
                acc[mt][1] = MFMA(aw[mt], b1, acc[mt][1]);
            }
            if (kb < KB - 1) {
#pragma unroll
                for (int mt = 0; mt < 4; ++mt) aw[mt] = awn[mt];
            }
        }
    }
    // relu -> packed bf16 pairs; position (q,mt,i) holds h1[kb*32+q*8+j] by construction
    unsigned int hp[2][4][2];
#pragma unroll
    for (int s = 0; s < 2; ++s)
#pragma unroll
        for (int mt = 0; mt < 4; ++mt) {
            hp[s][mt][0] = pack_bf2(fmaxf(acc[mt][s][0], 0.f), fmaxf(acc[mt][s][1], 0.f));
            hp[s][mt][1] = pack_bf2(fmaxf(acc[mt][s][2], 0.f), fmaxf(acc[mt][s][3], 0.f));
        }

    // ---- layer 2: A = W2 (LDS stream), B = h1 (own registers!) ----
    f32x4 acc2[4][2];
#pragma unroll
    for (int mt = 0; mt < 4; ++mt) {
        int base = ((mt >> 1) << 5) + (q << 3) + ((mt & 1) << 2);
        float4 bv = *(const float4*)(b2p + k * 64 + base);
        f32x4 b = {bv.x, bv.y, bv.z, bv.w};
        acc2[mt][0] = b; acc2[mt][1] = b;
    }
#pragma unroll
    for (int kb = 0; kb < 2; ++kb) {
        bf16x8 bh0 = frag_from_hp(hp[0], kb);
        bf16x8 bh1 = frag_from_hp(hp[1], kb);
#pragma unroll
        for (int mt = 0; mt < 4; ++mt) {
            bf16x8 a2 = *(const bf16x8*)(Wl + W2OB + ((kb * 4 + mt) << 10));
            acc2[mt][0] = MFMA(a2, bh0, acc2[mt][0]);
            acc2[mt][1] = MFMA(a2, bh1, acc2[mt][1]);
        }
    }
    // relu -> packed h2 (same permuted property)
#pragma unroll
    for (int s = 0; s < 2; ++s)
#pragma unroll
        for (int mt = 0; mt < 4; ++mt) {
            hp[s][mt][0] = pack_bf2(fmaxf(acc2[mt][s][0], 0.f), fmaxf(acc2[mt][s][1], 0.f));
            hp[s][mt][1] = pack_bf2(fmaxf(acc2[mt][s][2], 0.f), fmaxf(acc2[mt][s][3], 0.f));
        }

    // ---- layer 3: A = W3 padded to 16 rows (LDS stream), B = h2 (own registers) ----
    f32x4 acc3[2];
    if (MODE == 0) {
        float b3 = b3p[k];
        f32x4 z = {0.f, 0.f, 0.f, 0.f};
        if (q == 0) z[0] = b3;
        acc3[0] = z; acc3[1] = z;
    } else {
        f32x4 z = {0.f, 0.f, 0.f, 0.f};
        if (q < 2) {
            float4 bv = *(const float4*)(b3p + k * 8 + q * 4);
            z = {bv.x, bv.y, bv.z, bv.w};
        }
        acc3[0] = z; acc3[1] = z;
    }
#pragma unroll
    for (int kb = 0; kb < 2; ++kb) {
        bf16x8 a3 = *(const bf16x8*)(Wl + W3OB + (kb << 10));
#pragma unroll
        for (int s = 0; s < 2; ++s) acc3[s] = MFMA(a3, frag_from_hp(hp[s], kb), acc3[s]);
    }
    // ---- epilogue (C-layout: out-row = q*4+i, batch col = c) ----
#pragma unroll
    for (int s = 0; s < 2; ++s) {
        if (MODE == 0) {
            float v = __shfl(acc3[s][0], c, 64);  // row 0 lives in lanes 0..15 reg 0
            keyv[s] = fabsf(v) + 1e-10f;
        } else if (MODE == 1) {
#pragma unroll
            for (int i = 0; i < 4; ++i) ag[s][i] = 1.f / (1.f + __expf(-acc3[s][i]));
        } else {
#pragma unroll
            for (int i = 0; i < 4; ++i)
                outacc[s][i] += keyv[s] * ag[s][i] * (1.f / (1.f + __expf(-acc3[s][i])));
        }
    }
}

// ---------------- main kernel: 512 thr, grid 256 (1 block/CU), 2-phase LDS schedule --------
// R11: amdgpu_waves_per_eu(2,2) — truthful (145KB LDS forces 1 block/CU = 8 waves = 2/EU)
// and raises the VGPR allocator budget 128 -> 256. Theory: the backend's occupancy heuristic
// was capping at 128 (R3/R4: spilled at exactly 128 under both launch_bounds variants),
// which limits ds_read hoist depth to ~2-3 in flight vs the ~12 needed to cover ~120cyc
// LDS latency at 2 waves/SIMD. Watch: VGPR should rise >128 with WRITE_SIZE staying ~2MB.
__global__ __launch_bounds__(512)
__attribute__((amdgpu_waves_per_eu(2, 2)))
void qplex_main(
    const float* __restrict__ states, const float* __restrict__ actions,
    const __bf16* __restrict__ wbf,
    const float* __restrict__ b1k, const float* __restrict__ b2k, const float* __restrict__ b3k,
    const float* __restrict__ b1a, const float* __restrict__ b2a, const float* __restrict__ b3a,
    const float* __restrict__ b1c, const float* __restrict__ b2c, const float* __restrict__ b3c,
    float* __restrict__ out) {
    __shared__ __bf16 WB[SLAB_K_ELEMS];  // 145408 B: [A: key||agents 43008 elems][B: action]
    __bf16* RA = WB;
    __bf16* RB = WB + 2 * NET_ELEMS;

    const int tid = threadIdx.x;
    const int lane = tid & 63;
    const int wave = tid >> 6;
    const int q = lane >> 4;
    const int c = lane & 15;
    const int rowbase = blockIdx.x * 256 + wave * 32;

    // kick off staging of slab-0 key+agents before anything else
    stage(wbf, RA, 84, wave, lane);

    // ---- load this wave's 32 rows of states as B-fragments (lane c: row rowbase+s*16+c) ----
    bf16x8 xf[2][8];
#pragma unroll
    for (int s = 0; s < 2; ++s) {
        const float* srow = states + (size_t)(rowbase + s * 16 + c) * Sdim + q * 8;
#pragma unroll
        for (int kb = 0; kb < 8; ++kb)
            xf[s][kb] = cvt8(*(const float4*)(srow + kb * 32), *(const float4*)(srow + kb * 32 + 4));
    }

    float keyv[2];
    float ag[2][4];
    float outacc[2][4];
#pragma unroll
    for (int s = 0; s < 2; ++s) {
        keyv[s] = 0.f;
#pragma unroll
        for (int i = 0; i < 4; ++i) { ag[s][i] = 0.f; outacc[s][i] = 0.f; }
    }

    __syncthreads();  // drains slab-0 key+agents staging (vmcnt0 before barrier)

    for (int k = 0; k < Kk; ++k) {
        const __bf16* kslab = wbf + (size_t)k * SLAB_K_ELEMS;
        // --- phase A: key then agents (region A, sequential — no barrier between);
        //     prefetch action net -> region B ---
        stage(kslab + 2 * NET_ELEMS, RB, 58, wave, lane);
        compute_net<8, 0>(RA, xf, actions, rowbase, q, c, lane, k,
                          b1k, b2k, b3k, keyv, ag, outacc);
        compute_net<8, 1>(RA + NET_ELEMS, xf, actions, rowbase, q, c, lane, k,
                          b1a, b2a, b3a, keyv, ag, outacc);
        __syncthreads();
        // --- phase B: action net (region B); prefetch next slab's key+agents -> region A ---
        if (k < Kk - 1) stage(kslab + SLAB_K_ELEMS, RA, 84, wave, lane);
        compute_net<12, 2>(RB, xf, actions, rowbase, q, c, lane, k,
                           b1c, b2c, b3c, keyv, ag, outacc);
        __syncthreads();
    }

    // ---- store: rows q*4+i are agents a (q<2), col c is batch ----
    if (q < 2) {
#pragma unroll
        for (int s = 0; s < 2; ++s) {
            int r = rowbase + s * 16 + c;
            float4 v = {outacc[s][0], outacc[s][1], outacc[s][2], outacc[s][3]};
            *(float4*)(out + (size_t)r * Aag + q * 4) = v;
        }
    }
}

extern "C" void kernel_launch(void* const* d_in, const int* in_sizes, int n_in,
                              void* d_out, int out_size, void* d_ws, size_t ws_size,
                              hipStream_t stream) {
    const float* states = (const float*)d_in[0];
    const float* actions = (const float*)d_in[1];
    const float* kW1 = (const float*)d_in[2];
    const float* kb1 = (const float*)d_in[3];
    const float* kW2 = (const float*)d_in[4];
    const float* kb2 = (const float*)d_in[5];
    const float* kW3 = (const float*)d_in[6];
    const float* kb3 = (const float*)d_in[7];
    const float* aW1 = (const float*)d_in[8];
    const float* ab1 = (const float*)d_in[9];
    const float* aW2 = (const float*)d_in[10];
    const float* ab2 = (const float*)d_in[11];
    const float* aW3 = (const float*)d_in[12];
    const float* ab3 = (const float*)d_in[13];
    const float* cW1 = (const float*)d_in[14];
    const float* cb1 = (const float*)d_in[15];
    const float* cW2 = (const float*)d_in[16];
    const float* cb2 = (const float*)d_in[17];
    const float* cW3 = (const float*)d_in[18];
    const float* cb3 = (const float*)d_in[19];
    float* out = (float*)d_out;
    __bf16* wbf = (__bf16*)d_ws;  // 1,454,080 bytes of scratch

    prep_weights<<<355, 256, 0, stream>>>(kW1, aW1, cW1, kW2, aW2, cW2, kW3, aW3, cW3, wbf);
    qplex_main<<<256, 512, 0, stream>>>(states, actions, wbf, kb1, kb2, kb3,
                                        ab1, ab2, ab3, cb1, cb2, cb3, out);
}